// Round 10
// baseline (232.528 us; speedup 1.0000x reference)
//
#include <hip/hip_runtime.h>

typedef __bf16 bf16x8 __attribute__((ext_vector_type(8)));
typedef float  f32x4  __attribute__((ext_vector_type(4)));
typedef unsigned int u32x4 __attribute__((ext_vector_type(4)));
typedef unsigned short u16x8 __attribute__((ext_vector_type(8)));
typedef unsigned short u16x4 __attribute__((ext_vector_type(4)));
typedef short i16x4 __attribute__((ext_vector_type(4)));

__device__ __forceinline__ unsigned short f2bf(float f) {
    return __builtin_bit_cast(unsigned short, (__bf16)f);
}
__device__ __forceinline__ bf16x8 as_bf16x8(u32x4 v) {
    return __builtin_bit_cast(bf16x8, v);
}

#define AS1 __attribute__((address_space(1)))
#define AS3 __attribute__((address_space(3)))
__device__ __forceinline__ void gload_lds16(const void* g, void* l) {
    __builtin_amdgcn_global_load_lds((const AS1 void*)g, (AS3 void*)l, 16, 0, 0);
}

// Window-major permutation: m' groups the 4 members of each 2x2 spatial
// window consecutively. n = b*4096 + hh*64 + ww  ->  m' = (b*1024 +
// (hh>>1)*32 + (ww>>1))*4 + (hh&1)*2 + (ww&1).

// ---------------- prep: fused cast+permute+pool (one x read), weight transpose ----------------
__global__ __launch_bounds__(256) void k_prep(
        const float* __restrict__ x,
        const float* __restrict__ h_qkv_w, const float* __restrict__ l_q_w,
        const float* __restrict__ l_kv_w, const float* __restrict__ h_proj_w,
        const float* __restrict__ l_proj_w,
        unsigned short* __restrict__ xb, unsigned short* __restrict__ xpb,
        unsigned short* __restrict__ wcatT, unsigned short* __restrict__ lkvT,
        unsigned short* __restrict__ hprojT, unsigned short* __restrict__ lprojT) {
    int blk = blockIdx.x;
    if (blk < 2048) {
        // thread -> (window widx, 8-channel chunk c8). Reads the 4 window rows once:
        // emits 4 xb rows (m'-order: consecutive!) + 1 pooled xpb row. x read once, not twice.
        int t = blk * 256 + threadIdx.x;
        int widx = t >> 6, c8 = (t & 63) << 3;
        int b = widx >> 10, rem = widx & 1023;
        int h2 = rem >> 5, w2 = rem & 31;
        const float* base = x + ((size_t)(b << 12) + (h2 << 7) + (w2 << 1)) * 512 + c8;
        f32x4 acc0 = {}, acc1 = {};
        const int roff[4] = {0, 1, 64, 65};   // (dh,dw) = (0,0),(0,1),(1,0),(1,1)
#pragma unroll
        for (int j = 0; j < 4; j++) {
            const float* src = base + (size_t)roff[j] * 512;
            f32x4 v0 = *(const f32x4*)src;
            f32x4 v1 = *(const f32x4*)(src + 4);
            acc0 += v0; acc1 += v1;
            u16x8 o = { f2bf(v0[0]), f2bf(v0[1]), f2bf(v0[2]), f2bf(v0[3]),
                        f2bf(v1[0]), f2bf(v1[1]), f2bf(v1[2]), f2bf(v1[3]) };
            *(u16x8*)(xb + ((size_t)widx * 4 + j) * 512 + c8) = o;
        }
        acc0 *= 0.25f; acc1 *= 0.25f;
        u16x8 p = { f2bf(acc0[0]), f2bf(acc0[1]), f2bf(acc0[2]), f2bf(acc0[3]),
                    f2bf(acc1[0]), f2bf(acc1[1]), f2bf(acc1[2]), f2bf(acc1[3]) };
        *(u16x8*)(xpb + (size_t)widx * 512 + c8) = p;
    } else {
        // weights -> B^T bf16
        int i = (blk - 2048) * 256 + threadIdx.x;
        if (i < 262144) {
            int n = i >> 9, k = i & 511;
            float v = (n < 256) ? h_qkv_w[k * 256 + n] : l_q_w[k * 256 + (n - 256)];
            wcatT[i] = f2bf(v);
        } else if (i < 524288) {
            int j = i - 262144; int n = j >> 9, k = j & 511;
            lkvT[j] = f2bf(l_kv_w[k * 512 + n]);
        } else if (i < 589824) {
            int j = i - 524288; int n = j >> 8, k = j & 255;
            hprojT[j] = f2bf(h_proj_w[k * 256 + n]);
        } else {
            int j = i - 589824; int n = j >> 8, k = j & 255;
            lprojT[j] = f2bf(l_proj_w[k * 256 + n]);
        }
    }
}

// ---------------- GEMM core A: 128x128 tile, BK=64 as two BK=32 planes ----------------
// (R9: flat vs BK=32 -- kept for halved static barrier count.) Used by proj paths.
__device__ __forceinline__ void mm_core(
        const unsigned short* __restrict__ A, const unsigned short* __restrict__ Bt,
        size_t row0, int col0, int K,
        unsigned short* As, unsigned short* Bs, f32x4 (&acc)[4][4]) {
    const int tid = threadIdx.x;
    const int wave = tid >> 6, lane = tid & 63;
    const int m16 = lane & 15, quad = lane >> 4;
    const int wr = wave >> 1, wc = wave & 1;
    const int srow = lane >> 2;
    const int scol = (lane & 3) * 8;
    const unsigned short* Ap0 = A + (row0 + wave * 32 + srow) * (size_t)K + scol;
    const unsigned short* Ap1 = Ap0 + (size_t)16 * K;
    const unsigned short* Bp0 = Bt + (size_t)(col0 + wave * 32 + srow) * K + scol;
    const unsigned short* Bp1 = Bp0 + (size_t)16 * K;
    unsigned short* Al0 = As + wave * 1024;
    unsigned short* Al1 = As + wave * 1024 + 512;
    unsigned short* Bl0 = Bs + wave * 1024;
    unsigned short* Bl1 = Bs + wave * 1024 + 512;

    for (int k0 = 0; k0 < K; k0 += 64) {
        __syncthreads();
        gload_lds16(Ap0 + k0, Al0);
        gload_lds16(Ap1 + k0, Al1);
        gload_lds16(Bp0 + k0, Bl0);
        gload_lds16(Bp1 + k0, Bl1);
        gload_lds16(Ap0 + k0 + 32, Al0 + 4096);
        gload_lds16(Ap1 + k0 + 32, Al1 + 4096);
        gload_lds16(Bp0 + k0 + 32, Bl0 + 4096);
        gload_lds16(Bp1 + k0 + 32, Bl1 + 4096);
        __syncthreads();
#pragma unroll
        for (int kk = 0; kk < 2; kk++) {
            const unsigned short* Asp = As + kk * 4096;
            const unsigned short* Bsp = Bs + kk * 4096;
            bf16x8 af[4], bfr[4];
#pragma unroll
            for (int mi = 0; mi < 4; mi++)
                af[mi] = as_bf16x8(*(const u32x4*)(Asp + (wr * 64 + mi * 16 + m16) * 32 + quad * 8));
#pragma unroll
            for (int ni = 0; ni < 4; ni++)
                bfr[ni] = as_bf16x8(*(const u32x4*)(Bsp + (wc * 64 + ni * 16 + m16) * 32 + quad * 8));
#pragma unroll
            for (int mi = 0; mi < 4; mi++)
#pragma unroll
                for (int ni = 0; ni < 4; ni++)
                    acc[mi][ni] = __builtin_amdgcn_mfma_f32_16x16x32_bf16(af[mi], bfr[ni], acc[mi][ni], 0, 0, 0);
        }
    }
}

// ---------------- GEMM core B: 128x256 tile, BK=64, acc[4][8] ----------------
// 2x MFMA per staged byte vs core A (64 MFMA on 12 ds_read_b128 per K-step/wave) and
// each A row-stripe read by 2 blocks instead of 4. VGPR ~200: fits (256,2) without the
// (256,4) clamp (R2/R4). Per-wave output 64x128 (wr=row half, wc=col half of 256).
__device__ __forceinline__ void mm_core256(
        const unsigned short* __restrict__ A, const unsigned short* __restrict__ Bt,
        size_t row0, int col0, int K,
        unsigned short* As, unsigned short* Bs, f32x4 (&acc)[4][8]) {
    const int tid = threadIdx.x;
    const int wave = tid >> 6, lane = tid & 63;
    const int m16 = lane & 15, quad = lane >> 4;
    const int wr = wave >> 1, wc = wave & 1;
    const int srow = lane >> 2;
    const int scol = (lane & 3) * 8;
    const unsigned short* Ap0 = A + (row0 + wave * 32 + srow) * (size_t)K + scol;
    const unsigned short* Ap1 = Ap0 + (size_t)16 * K;
    const unsigned short* Bp0 = Bt + (size_t)(col0 + wave * 64 + srow) * K + scol;
    const unsigned short* Bp1 = Bp0 + (size_t)16 * K;
    const unsigned short* Bp2 = Bp0 + (size_t)32 * K;
    const unsigned short* Bp3 = Bp0 + (size_t)48 * K;
    unsigned short* Al0 = As + wave * 1024;          // A plane: [128][32] row-major
    unsigned short* Al1 = As + wave * 1024 + 512;
    unsigned short* Bl0 = Bs + wave * 2048;          // B plane: [256][32] row-major
    unsigned short* Bl1 = Bs + wave * 2048 + 512;
    unsigned short* Bl2 = Bs + wave * 2048 + 1024;
    unsigned short* Bl3 = Bs + wave * 2048 + 1536;

    for (int k0 = 0; k0 < K; k0 += 64) {
        __syncthreads();
        gload_lds16(Ap0 + k0, Al0);
        gload_lds16(Ap1 + k0, Al1);
        gload_lds16(Bp0 + k0, Bl0);
        gload_lds16(Bp1 + k0, Bl1);
        gload_lds16(Bp2 + k0, Bl2);
        gload_lds16(Bp3 + k0, Bl3);
        gload_lds16(Ap0 + k0 + 32, Al0 + 4096);      // plane 1: A at +4096, B at +8192
        gload_lds16(Ap1 + k0 + 32, Al1 + 4096);
        gload_lds16(Bp0 + k0 + 32, Bl0 + 8192);
        gload_lds16(Bp1 + k0 + 32, Bl1 + 8192);
        gload_lds16(Bp2 + k0 + 32, Bl2 + 8192);
        gload_lds16(Bp3 + k0 + 32, Bl3 + 8192);
        __syncthreads();
#pragma unroll
        for (int kk = 0; kk < 2; kk++) {
            const unsigned short* Asp = As + kk * 4096;
            const unsigned short* Bsp = Bs + kk * 8192;
            bf16x8 af[4], bfr[8];
#pragma unroll
            for (int mi = 0; mi < 4; mi++)
                af[mi] = as_bf16x8(*(const u32x4*)(Asp + (wr * 64 + mi * 16 + m16) * 32 + quad * 8));
#pragma unroll
            for (int ni = 0; ni < 8; ni++)
                bfr[ni] = as_bf16x8(*(const u32x4*)(Bsp + (wc * 128 + ni * 16 + m16) * 32 + quad * 8));
#pragma unroll
            for (int mi = 0; mi < 4; mi++)
#pragma unroll
                for (int ni = 0; ni < 8; ni++)
                    acc[mi][ni] = __builtin_amdgcn_mfma_f32_16x16x32_bf16(af[mi], bfr[ni], acc[mi][ni], 0, 0, 0);
        }
    }
}

// ---------------- launch 2: gemm1 (x@[hqkv|lq] + fused hifi) and kv-gemm (+fused V^T) ----------------
// 128x256 tile: col0 in {0,256} so each block is PURELY dbuf/qbuf (or kbuf/vT).
// Grid 640 = 512 gemm1 (256 row x 2 col) + 128 kv (64 x 2). XCD-chunked swizzle (640%8==0).
__global__ __launch_bounds__(256, 2) void k_mm512(
        const unsigned short* __restrict__ xb, const unsigned short* __restrict__ xpb,
        const unsigned short* __restrict__ wcatT, const unsigned short* __restrict__ lkvT,
        unsigned short* __restrict__ dbuf, unsigned short* __restrict__ qbuf,
        unsigned short* __restrict__ kbuf, unsigned short* __restrict__ vT) {
    __shared__ __align__(16) unsigned short As[128 * 64];   // 16 KB
    __shared__ __align__(16) unsigned short Bs[256 * 64];   // 32 KB
    const int bid = blockIdx.x;                       // 0..639
    const int flat = (bid & 7) * 80 + (bid >> 3);
    const bool isg1 = flat < 512;
    const unsigned short* A;
    const unsigned short* Bt;
    size_t row0; int col0;
    if (isg1) { A = xb;  Bt = wcatT; row0 = (size_t)(flat >> 1) * 128; col0 = (flat & 1) * 256; }
    else { int f = flat - 512; A = xpb; Bt = lkvT; row0 = (size_t)(f >> 1) * 128; col0 = (f & 1) * 256; }

    f32x4 acc[4][8] = {};
    mm_core256(A, Bt, row0, col0, 512, As, Bs, acc);

    const int tid = threadIdx.x;
    const int wave = tid >> 6, lane = tid & 63;
    const int m16 = lane & 15, quad = lane >> 4;
    const int wr = wave >> 1, wc = wave & 1;

    if (isg1) {
        if (col0 == 0) {
            // hifi: lane's 4 rows are one 2x2 window (m'-order) -> dbuf = mean - val
#pragma unroll
            for (int mi = 0; mi < 4; mi++)
#pragma unroll
                for (int ni = 0; ni < 8; ni++) {
                    const int col = wc * 128 + ni * 16 + m16;
                    const size_t mb = row0 + wr * 64 + mi * 16 + quad * 4;
                    float v0 = acc[mi][ni][0], v1 = acc[mi][ni][1];
                    float v2 = acc[mi][ni][2], v3 = acc[mi][ni][3];
                    float m = 0.25f * ((v0 + v1) + (v2 + v3));
                    dbuf[(mb + 0) * 256 + col] = f2bf(m - v0);
                    dbuf[(mb + 1) * 256 + col] = f2bf(m - v1);
                    dbuf[(mb + 2) * 256 + col] = f2bf(m - v2);
                    dbuf[(mb + 3) * 256 + col] = f2bf(m - v3);
                }
        } else {
            // Q (unscaled -- R5 lesson: softmax scale stays in attn's __expf)
#pragma unroll
            for (int mi = 0; mi < 4; mi++)
#pragma unroll
                for (int ni = 0; ni < 8; ni++) {
                    const int col = wc * 128 + ni * 16 + m16;
                    const size_t mb = row0 + wr * 64 + mi * 16 + quad * 4;
#pragma unroll
                    for (int r = 0; r < 4; r++)
                        qbuf[(mb + r) * 256 + col] = f2bf(acc[mi][ni][r]);
                }
        }
    } else {
        if (col0 == 0) {
#pragma unroll
            for (int mi = 0; mi < 4; mi++)
#pragma unroll
                for (int ni = 0; ni < 8; ni++) {
                    const int col = wc * 128 + ni * 16 + m16;
                    const size_t row = row0 + wr * 64 + mi * 16 + quad * 4;
#pragma unroll
                    for (int r = 0; r < 4; r++)
                        kbuf[(row + r) * 256 + col] = f2bf(acc[mi][ni][r]);
                }
        } else {
            // V stored transposed: vT[(b*4+h)*64 + d][kv], lane's 4 rows = 4 consecutive kv
#pragma unroll
            for (int mi = 0; mi < 4; mi++)
#pragma unroll
                for (int ni = 0; ni < 8; ni++) {
                    const int d = wc * 128 + ni * 16 + m16;
                    const int hh = d >> 6, dd = d & 63;
                    const size_t kvg = row0 + wr * 64 + mi * 16 + quad * 4;
                    const int b = (int)(kvg >> 10), kv = (int)(kvg & 1023);
                    u16x4 pk = { f2bf(acc[mi][ni][0]), f2bf(acc[mi][ni][1]),
                                 f2bf(acc[mi][ni][2]), f2bf(acc[mi][ni][3]) };
                    *(u16x4*)(vT + (((size_t)(b * 4 + hh) * 64 + dd) << 10) + kv) = pk;
                }
        }
    }
}

// ---------------- launch 3: attention (blocks 0..511) + hi-fi projection (512..1023) ----
// (256,2) launch bounds -- NOT (256,4): min-waves>=4 clamps VGPR to 64 and spills (R2/R4).
// Each CU holds attn + hiproj blocks concurrently; hiproj fills attn's idle pipes.
// Attn path = R6 proven body (expf, lp on VALU, no ones-MFMA (R7), no setprio (R3)).
__global__ __launch_bounds__(256, 2) void k_attn_hiproj(
        const unsigned short* __restrict__ qbuf,  // [32768,256] m'-order
        const unsigned short* __restrict__ kbuf,  // [8192,256]
        const unsigned short* __restrict__ vT,    // [32][64][1024]
        unsigned short* __restrict__ aout,        // [32768,256] m'-order
        const unsigned short* __restrict__ dbuf,  // [32768,256] m'-order
        const unsigned short* __restrict__ hprojT,
        const float* __restrict__ h_proj_b,
        float* __restrict__ out) {
    __shared__ __align__(16) unsigned short smem[4 * 64 * 72];  // 36,864 B union (mm needs 32K)
    const int bx = blockIdx.x;
    const int tid = threadIdx.x;
    const int wave = tid >> 6, lane = tid & 63;
    const int m16 = lane & 15, quad = lane >> 4;

    if (bx < 512) {
        // ---------------- attention (R6 body) ----------------
        unsigned short* Kb = smem;                 // [2][64*72]
        unsigned short* Vb = smem + 2 * 64 * 72;   // [2][64*72]
        const int qtile = bx & 15, bh = bx >> 4;
        const int b = bh >> 2, h = bh & 3;

        bf16x8 qf[4][2];
        const size_t qrow0 = (size_t)b * 4096 + qtile * 256 + wave * 64;
#pragma unroll
        for (int qh = 0; qh < 4; qh++) {
            const unsigned short* qp = qbuf + (qrow0 + qh * 16 + m16) * 256 + h * 64 + quad * 8;
            qf[qh][0] = as_bf16x8(*(const u32x4*)qp);
            qf[qh][1] = as_bf16x8(*(const u32x4*)(qp + 32));
        }

        f32x4 o[4][4] = {};
        float lp[4] = {0.f, 0.f, 0.f, 0.f};

        const int sr = tid >> 3;       // 0..31
        const int sc = tid & 7;        // 16B chunk
        const unsigned short* kg = kbuf + ((size_t)b * 1024) * 256 + h * 64 + sc * 8;
        const unsigned short* vg = vT + ((size_t)bh * 64) * 1024 + sc * 8;

        u32x4 s0 = *(const u32x4*)(kg + (size_t)sr * 256);
        u32x4 s1 = *(const u32x4*)(kg + (size_t)(sr + 32) * 256);
        u32x4 s2 = *(const u32x4*)(vg + (size_t)sr * 1024);
        u32x4 s3 = *(const u32x4*)(vg + (size_t)(sr + 32) * 1024);
        *(u32x4*)&Kb[sr * 72 + sc * 8] = s0;
        *(u32x4*)&Kb[(sr + 32) * 72 + sc * 8] = s1;
        *(u32x4*)&Vb[sr * 72 + sc * 8] = s2;
        *(u32x4*)&Vb[(sr + 32) * 72 + sc * 8] = s3;

        for (int it = 0; it < 16; ++it) {
            const int cur = (it & 1) * 4608, nxt = cur ^ 4608;
            __syncthreads();
            if (it + 1 < 16) {
                const size_t kvb = (size_t)(it + 1) * 64;
                s0 = *(const u32x4*)(kg + (kvb + sr) * 256);
                s1 = *(const u32x4*)(kg + (kvb + sr + 32) * 256);
                s2 = *(const u32x4*)(vg + kvb + (size_t)sr * 1024);
                s3 = *(const u32x4*)(vg + kvb + (size_t)(sr + 32) * 1024);
            }

#pragma unroll
            for (int mt = 0; mt < 4; mt++) {
                // S^T = K Q^T : C col = q = m16, row = kv = mt*16 + quad*4 + r
                const unsigned short* kp = &Kb[cur + (mt * 16 + m16) * 72 + quad * 8];
                const bf16x8 kf0 = as_bf16x8(*(const u32x4*)kp);
                const bf16x8 kf1 = as_bf16x8(*(const u32x4*)(kp + 32));
                f32x4 st[4];
#pragma unroll
                for (int qh = 0; qh < 4; qh++) {
                    f32x4 z = {};
                    z = __builtin_amdgcn_mfma_f32_16x16x32_bf16(kf0, qf[qh][0], z, 0, 0, 0);
                    st[qh] = __builtin_amdgcn_mfma_f32_16x16x32_bf16(kf1, qf[qh][1], z, 0, 0, 0);
                }
                // P = exp(S*scale); packed P is directly the K=16 MFMA A-frag
                i16x4 pa[4];
#pragma unroll
                for (int qh = 0; qh < 4; qh++) {
                    float p0 = __expf(st[qh][0] * 0.125f);
                    float p1 = __expf(st[qh][1] * 0.125f);
                    float p2 = __expf(st[qh][2] * 0.125f);
                    float p3 = __expf(st[qh][3] * 0.125f);
                    lp[qh] += (p0 + p1) + (p2 + p3);
                    u16x4 pk = { f2bf(p0), f2bf(p1), f2bf(p2), f2bf(p3) };
                    pa[qh] = __builtin_bit_cast(i16x4, pk);
                }
#pragma unroll
                for (int nt = 0; nt < 4; nt++) {
                    const i16x4 vb = *(const i16x4*)&Vb[cur + (nt * 16 + m16) * 72 + mt * 16 + quad * 4];
#pragma unroll
                    for (int qh = 0; qh < 4; qh++)
                        o[qh][nt] = __builtin_amdgcn_mfma_f32_16x16x16bf16_1k(pa[qh], vb, o[qh][nt], 0, 0, 0);
                }
            }

            if (it + 1 < 16) {
                *(u32x4*)&Kb[nxt + sr * 72 + sc * 8] = s0;
                *(u32x4*)&Kb[nxt + (sr + 32) * 72 + sc * 8] = s1;
                *(u32x4*)&Vb[nxt + sr * 72 + sc * 8] = s2;
                *(u32x4*)&Vb[nxt + (sr + 32) * 72 + sc * 8] = s3;
            }
        }

#pragma unroll
        for (int qh = 0; qh < 4; qh++) {
            float l = lp[qh];
            l += __shfl_xor(l, 16);
            l += __shfl_xor(l, 32);
            f32x4 linv;
#pragma unroll
            for (int r = 0; r < 4; r++)
                linv[r] = __builtin_amdgcn_rcpf(__shfl(l, quad * 4 + r));
#pragma unroll
            for (int nt = 0; nt < 4; nt++)
#pragma unroll
                for (int r = 0; r < 4; r++)
                    aout[(qrow0 + qh * 16 + quad * 4 + r) * 256 + h * 64 + nt * 16 + m16] =
                        f2bf(o[qh][nt][r] * linv[r]);
        }
    } else {
        // ---------------- hi-fi projection GEMM ----------------
        unsigned short* As = smem;
        unsigned short* Bs = smem + 128 * 64;      // core A: 8192-short planes x2
        const int f = bx - 512;                    // 0..511
        const size_t row0 = (size_t)(f >> 1) * 128;
        const int col0 = (f & 1) * 128;

        f32x4 acc[4][4] = {};
        mm_core(dbuf, hprojT, row0, col0, 256, As, Bs, acc);

        const int wr = wave >> 1, wc = wave & 1;
#pragma unroll
        for (int mi = 0; mi < 4; mi++)
#pragma unroll
            for (int ni = 0; ni < 4; ni++) {
                const int col = col0 + wc * 64 + ni * 16 + m16;
                const float bv = h_proj_b[col];
                const size_t mb = row0 + wr * 64 + mi * 16 + quad * 4;
                const int widx = (int)(mb >> 2);
                const int b = widx >> 10, rem = widx & 1023;
                const int h2 = rem >> 5, w2 = rem & 31;
                const size_t nb = ((size_t)b << 12) + (h2 << 7) + (w2 << 1);
                float* op = out + nb * 512 + col;
                op[0]            = acc[mi][ni][0] + bv;
                op[512]          = acc[mi][ni][1] + bv;
                op[64 * 512]     = acc[mi][ni][2] + bv;
                op[65 * 512]     = acc[mi][ni][3] + bv;
            }
    }
}

// ---------------- launch 4: lo-fi projection GEMM, un-permuting epilogue ----------------
__global__ __launch_bounds__(256, 2) void k_mmproj_lo(
        const unsigned short* __restrict__ aout,
        const unsigned short* __restrict__ lprojT,
        const float* __restrict__ l_proj_b,
        float* __restrict__ out) {
    __shared__ __align__(16) unsigned short As[128 * 64];
    __shared__ __align__(16) unsigned short Bs[128 * 64];
    const int bid = blockIdx.x;                  // 0..511, 512%8==0 -> bijective
    const int f = (bid & 7) * 64 + (bid >> 3);
    const size_t row0 = (size_t)(f >> 1) * 128;
    const int col0 = (f & 1) * 128;

    f32x4 acc[4][4] = {};
    mm_core(aout, lprojT, row0, col0, 256, As, Bs, acc);

    const int tid = threadIdx.x;
    const int wave = tid >> 6, lane = tid & 63;
    const int m16 = lane & 15, quad = lane >> 4;
    const int wr = wave >> 1, wc = wave & 1;

#pragma unroll
    for (int mi = 0; mi < 4; mi++)
#pragma unroll
        for (int ni = 0; ni < 4; ni++) {
            const int col = col0 + wc * 64 + ni * 16 + m16;
            const float bv = l_proj_b[col];
            const size_t mb = row0 + wr * 64 + mi * 16 + quad * 4;
            const int widx = (int)(mb >> 2);
            const int b = widx >> 10, rem = widx & 1023;
            const int h2 = rem >> 5, w2 = rem & 31;
            const size_t nb = ((size_t)b << 12) + (h2 << 7) + (w2 << 1);
            float* op = out + nb * 512 + 256 + col;
            op[0]            = acc[mi][ni][0] + bv;
            op[512]          = acc[mi][ni][1] + bv;
            op[64 * 512]     = acc[mi][ni][2] + bv;
            op[65 * 512]     = acc[mi][ni][3] + bv;
        }
}

// ---------------- launcher ----------------

extern "C" void kernel_launch(void* const* d_in, const int* in_sizes, int n_in,
                              void* d_out, int out_size, void* d_ws, size_t ws_size,
                              hipStream_t stream) {
    (void)in_sizes; (void)n_in; (void)out_size; (void)ws_size;
    const float* x        = (const float*)d_in[0];
    const float* l_q_w    = (const float*)d_in[2];
    const float* l_kv_w   = (const float*)d_in[3];
    const float* l_proj_w = (const float*)d_in[4];
    const float* l_proj_b = (const float*)d_in[5];
    const float* h_qkv_w  = (const float*)d_in[6];
    const float* h_proj_w = (const float*)d_in[7];
    const float* h_proj_b = (const float*)d_in[8];
    float* out = (float*)d_out;

    char* ws = (char*)d_ws;
    unsigned short* xb     = (unsigned short*)(ws);             // 33.5MB, dead after mm512
    unsigned short* aout   = (unsigned short*)(ws);             // 16.8MB, overlays xb
    unsigned short* dbuf   = (unsigned short*)(ws + 33554432);  // 16.8MB
    unsigned short* qbuf   = (unsigned short*)(ws + 50331648);  // 16.8MB
    unsigned short* kbuf   = (unsigned short*)(ws + 67108864);  // 4.2MB
    unsigned short* vT     = (unsigned short*)(ws + 71303168);  // 4.2MB
    unsigned short* xpb    = (unsigned short*)(ws + 75497472);  // 8.4MB
    unsigned short* wcatT  = (unsigned short*)(ws + 83886080);
    unsigned short* lkvT   = (unsigned short*)(ws + 84410368);
    unsigned short* hprojT = (unsigned short*)(ws + 84934656);
    unsigned short* lprojT = (unsigned short*)(ws + 85065728);
    // total ws requirement: 85,196,800 B (same as prior rounds)

    // fused cast+pool (2048) + weight transpose (2560)
    k_prep<<<4608, 256, 0, stream>>>(x, h_qkv_w, l_q_w, l_kv_w, h_proj_w, l_proj_w,
                                     xb, xpb, wcatT, lkvT, hprojT, lprojT);
    // gemm1 (512 blocks) + kv-gemm (128 blocks), 128x256 tiles, XCD swizzle
    k_mm512<<<640, 256, 0, stream>>>(xb, xpb, wcatT, lkvT, dbuf, qbuf, kbuf, vT);
    // attention (0..511) co-resident with hi-proj (512..1023)
    // (aout overlays xb -- xb dead after mm512)
    k_attn_hiproj<<<1024, 256, 0, stream>>>(qbuf, kbuf, vT, aout, dbuf, hprojT, h_proj_b, out);
    // lo-proj + bias + un-permute into out
    k_mmproj_lo<<<512, 256, 0, stream>>>(aout, lprojT, l_proj_b, out);
}

// Round 11
// 223.962 us; speedup vs baseline: 1.0382x; 1.0382x over previous
//
#include <hip/hip_runtime.h>

typedef __bf16 bf16x8 __attribute__((ext_vector_type(8)));
typedef float  f32x4  __attribute__((ext_vector_type(4)));
typedef unsigned int u32x4 __attribute__((ext_vector_type(4)));
typedef unsigned short u16x8 __attribute__((ext_vector_type(8)));
typedef unsigned short u16x4 __attribute__((ext_vector_type(4)));
typedef short i16x4 __attribute__((ext_vector_type(4)));

__device__ __forceinline__ unsigned short f2bf(float f) {
    return __builtin_bit_cast(unsigned short, (__bf16)f);
}
__device__ __forceinline__ bf16x8 as_bf16x8(u32x4 v) {
    return __builtin_bit_cast(bf16x8, v);
}

#define AS1 __attribute__((address_space(1)))
#define AS3 __attribute__((address_space(3)))
__device__ __forceinline__ void gload_lds16(const void* g, void* l) {
    __builtin_amdgcn_global_load_lds((const AS1 void*)g, (AS3 void*)l, 16, 0, 0);
}

// Window-major permutation: m' groups the 4 members of each 2x2 spatial
// window consecutively. n = b*4096 + hh*64 + ww  ->  m' = (b*1024 +
// (hh>>1)*32 + (ww>>1))*4 + (hh&1)*2 + (ww&1).

// ---------------- prep: fused cast+permute+pool (one x read), weight transpose ----------------
__global__ __launch_bounds__(256) void k_prep(
        const float* __restrict__ x,
        const float* __restrict__ h_qkv_w, const float* __restrict__ l_q_w,
        const float* __restrict__ l_kv_w, const float* __restrict__ h_proj_w,
        const float* __restrict__ l_proj_w,
        unsigned short* __restrict__ xb, unsigned short* __restrict__ xpb,
        unsigned short* __restrict__ wcatT, unsigned short* __restrict__ lkvT,
        unsigned short* __restrict__ hprojT, unsigned short* __restrict__ lprojT) {
    int blk = blockIdx.x;
    if (blk < 2048) {
        // thread -> (window widx, 8-channel chunk c8). Reads the 4 window rows once:
        // emits 4 xb rows (m'-order: consecutive!) + 1 pooled xpb row. x read once, not twice.
        int t = blk * 256 + threadIdx.x;
        int widx = t >> 6, c8 = (t & 63) << 3;
        int b = widx >> 10, rem = widx & 1023;
        int h2 = rem >> 5, w2 = rem & 31;
        const float* base = x + ((size_t)(b << 12) + (h2 << 7) + (w2 << 1)) * 512 + c8;
        f32x4 acc0 = {}, acc1 = {};
        const int roff[4] = {0, 1, 64, 65};   // (dh,dw) = (0,0),(0,1),(1,0),(1,1)
#pragma unroll
        for (int j = 0; j < 4; j++) {
            const float* src = base + (size_t)roff[j] * 512;
            f32x4 v0 = *(const f32x4*)src;
            f32x4 v1 = *(const f32x4*)(src + 4);
            acc0 += v0; acc1 += v1;
            u16x8 o = { f2bf(v0[0]), f2bf(v0[1]), f2bf(v0[2]), f2bf(v0[3]),
                        f2bf(v1[0]), f2bf(v1[1]), f2bf(v1[2]), f2bf(v1[3]) };
            *(u16x8*)(xb + ((size_t)widx * 4 + j) * 512 + c8) = o;
        }
        acc0 *= 0.25f; acc1 *= 0.25f;
        u16x8 p = { f2bf(acc0[0]), f2bf(acc0[1]), f2bf(acc0[2]), f2bf(acc0[3]),
                    f2bf(acc1[0]), f2bf(acc1[1]), f2bf(acc1[2]), f2bf(acc1[3]) };
        *(u16x8*)(xpb + (size_t)widx * 512 + c8) = p;
    } else {
        // weights -> B^T bf16
        int i = (blk - 2048) * 256 + threadIdx.x;
        if (i < 262144) {
            int n = i >> 9, k = i & 511;
            float v = (n < 256) ? h_qkv_w[k * 256 + n] : l_q_w[k * 256 + (n - 256)];
            wcatT[i] = f2bf(v);
        } else if (i < 524288) {
            int j = i - 262144; int n = j >> 9, k = j & 511;
            lkvT[j] = f2bf(l_kv_w[k * 512 + n]);
        } else if (i < 589824) {
            int j = i - 524288; int n = j >> 8, k = j & 255;
            hprojT[j] = f2bf(h_proj_w[k * 256 + n]);
        } else {
            int j = i - 589824; int n = j >> 8, k = j & 255;
            lprojT[j] = f2bf(l_proj_w[k * 256 + n]);
        }
    }
}

// ---------------- shared GEMM core: 128x128 tile, BK=64 as two BK=32 planes ----------------
// (R9: flat vs BK=32 -- kept for halved static barrier count. R10's 128x256 core sped
// mm512 ~10us but poisoned the following attn dispatch's L2 locality by ~15us -- reverted.)
__device__ __forceinline__ void mm_core(
        const unsigned short* __restrict__ A, const unsigned short* __restrict__ Bt,
        size_t row0, int col0, int K,
        unsigned short* As, unsigned short* Bs, f32x4 (&acc)[4][4]) {
    const int tid = threadIdx.x;
    const int wave = tid >> 6, lane = tid & 63;
    const int m16 = lane & 15, quad = lane >> 4;
    const int wr = wave >> 1, wc = wave & 1;
    const int srow = lane >> 2;
    const int scol = (lane & 3) * 8;
    const unsigned short* Ap0 = A + (row0 + wave * 32 + srow) * (size_t)K + scol;
    const unsigned short* Ap1 = Ap0 + (size_t)16 * K;
    const unsigned short* Bp0 = Bt + (size_t)(col0 + wave * 32 + srow) * K + scol;
    const unsigned short* Bp1 = Bp0 + (size_t)16 * K;
    unsigned short* Al0 = As + wave * 1024;
    unsigned short* Al1 = As + wave * 1024 + 512;
    unsigned short* Bl0 = Bs + wave * 1024;
    unsigned short* Bl1 = Bs + wave * 1024 + 512;

    for (int k0 = 0; k0 < K; k0 += 64) {
        __syncthreads();
        gload_lds16(Ap0 + k0, Al0);
        gload_lds16(Ap1 + k0, Al1);
        gload_lds16(Bp0 + k0, Bl0);
        gload_lds16(Bp1 + k0, Bl1);
        gload_lds16(Ap0 + k0 + 32, Al0 + 4096);
        gload_lds16(Ap1 + k0 + 32, Al1 + 4096);
        gload_lds16(Bp0 + k0 + 32, Bl0 + 4096);
        gload_lds16(Bp1 + k0 + 32, Bl1 + 4096);
        __syncthreads();
#pragma unroll
        for (int kk = 0; kk < 2; kk++) {
            const unsigned short* Asp = As + kk * 4096;
            const unsigned short* Bsp = Bs + kk * 4096;
            bf16x8 af[4], bfr[4];
#pragma unroll
            for (int mi = 0; mi < 4; mi++)
                af[mi] = as_bf16x8(*(const u32x4*)(Asp + (wr * 64 + mi * 16 + m16) * 32 + quad * 8));
#pragma unroll
            for (int ni = 0; ni < 4; ni++)
                bfr[ni] = as_bf16x8(*(const u32x4*)(Bsp + (wc * 64 + ni * 16 + m16) * 32 + quad * 8));
#pragma unroll
            for (int mi = 0; mi < 4; mi++)
#pragma unroll
                for (int ni = 0; ni < 4; ni++)
                    acc[mi][ni] = __builtin_amdgcn_mfma_f32_16x16x32_bf16(af[mi], bfr[ni], acc[mi][ni], 0, 0, 0);
        }
    }
}

// ---------------- launch 2: gemm1 (x@[hqkv|lq] + fused hifi) and kv-gemm (+fused V^T) ----------------
// XCD-chunked swizzle: consecutive original flat ids (= same A row-stripe, different
// col tile) are placed on the SAME XCD so the stripe is fetched into one L2 once.
// NOTE (R10): do NOT widen this to 128x256 tiles -- it changes the kv/q buffer L2
// placement and slows the following attn dispatch by ~15us (58 -> 73.5).
__global__ __launch_bounds__(256, 2) void k_mm512(
        const unsigned short* __restrict__ xb, const unsigned short* __restrict__ xpb,
        const unsigned short* __restrict__ wcatT, const unsigned short* __restrict__ lkvT,
        unsigned short* __restrict__ dbuf, unsigned short* __restrict__ qbuf,
        unsigned short* __restrict__ kbuf, unsigned short* __restrict__ vT) {
    __shared__ __align__(16) unsigned short As[128 * 64];
    __shared__ __align__(16) unsigned short Bs[128 * 64];
    const int bid = blockIdx.x;                       // 0..1279, 1280%8==0 -> bijective
    const int flat = (bid & 7) * 160 + (bid >> 3);
    const bool isg1 = flat < 1024;
    const unsigned short* A;
    const unsigned short* Bt;
    size_t row0; int col0;
    if (isg1) { A = xb;  Bt = wcatT; row0 = (size_t)(flat >> 2) * 128; col0 = (flat & 3) * 128; }
    else { int f = flat - 1024; A = xpb; Bt = lkvT; row0 = (size_t)(f >> 2) * 128; col0 = (f & 3) * 128; }

    f32x4 acc[4][4] = {};
    mm_core(A, Bt, row0, col0, 512, As, Bs, acc);

    const int tid = threadIdx.x;
    const int wave = tid >> 6, lane = tid & 63;
    const int m16 = lane & 15, quad = lane >> 4;
    const int wr = wave >> 1, wc = wave & 1;

    if (isg1) {
        if (col0 < 256) {
            // hifi: lane's 4 rows are one 2x2 window (m'-order) -> dbuf = mean - val
#pragma unroll
            for (int mi = 0; mi < 4; mi++)
#pragma unroll
                for (int ni = 0; ni < 4; ni++) {
                    const int col = col0 + wc * 64 + ni * 16 + m16;
                    const size_t mb = row0 + wr * 64 + mi * 16 + quad * 4;
                    float v0 = acc[mi][ni][0], v1 = acc[mi][ni][1];
                    float v2 = acc[mi][ni][2], v3 = acc[mi][ni][3];
                    float m = 0.25f * ((v0 + v1) + (v2 + v3));
                    dbuf[(mb + 0) * 256 + col] = f2bf(m - v0);
                    dbuf[(mb + 1) * 256 + col] = f2bf(m - v1);
                    dbuf[(mb + 2) * 256 + col] = f2bf(m - v2);
                    dbuf[(mb + 3) * 256 + col] = f2bf(m - v3);
                }
        } else {
            // Q (unscaled -- R5 lesson: softmax scale stays in attn's __expf, whose
            // v_mul co-issues for free; __builtin_exp2f's denormal-guard lowering
            // cost ~14us of serial VALU)
#pragma unroll
            for (int mi = 0; mi < 4; mi++)
#pragma unroll
                for (int ni = 0; ni < 4; ni++) {
                    const int col = col0 - 256 + wc * 64 + ni * 16 + m16;
                    const size_t mb = row0 + wr * 64 + mi * 16 + quad * 4;
#pragma unroll
                    for (int r = 0; r < 4; r++)
                        qbuf[(mb + r) * 256 + col] = f2bf(acc[mi][ni][r]);
                }
        }
    } else {
        if (col0 < 256) {
#pragma unroll
            for (int mi = 0; mi < 4; mi++)
#pragma unroll
                for (int ni = 0; ni < 4; ni++) {
                    const int col = col0 + wc * 64 + ni * 16 + m16;
                    const size_t row = row0 + wr * 64 + mi * 16 + quad * 4;
#pragma unroll
                    for (int r = 0; r < 4; r++)
                        kbuf[(row + r) * 256 + col] = f2bf(acc[mi][ni][r]);
                }
        } else {
            // V stored transposed: vT[(b*4+h)*64 + d][kv], lane's 4 rows = 4 consecutive kv
#pragma unroll
            for (int mi = 0; mi < 4; mi++)
#pragma unroll
                for (int ni = 0; ni < 4; ni++) {
                    const int d = col0 - 256 + wc * 64 + ni * 16 + m16;
                    const int hh = d >> 6, dd = d & 63;
                    const size_t kvg = row0 + wr * 64 + mi * 16 + quad * 4;
                    const int b = (int)(kvg >> 10), kv = (int)(kvg & 1023);
                    u16x4 pk = { f2bf(acc[mi][ni][0]), f2bf(acc[mi][ni][1]),
                                 f2bf(acc[mi][ni][2]), f2bf(acc[mi][ni][3]) };
                    *(u16x4*)(vT + (((size_t)(b * 4 + hh) * 64 + dd) << 10) + kv) = pk;
                }
        }
    }
}

// ---------------- launch 3: attention (blocks 0..511) + hi-fi projection (512..1023) ----
// (256,2) launch bounds -- NOT (256,4): min-waves>=4 clamps VGPR to 64 and spills (R2/R4).
// Each CU holds ~2 attn + ~2 hiproj blocks concurrently; hiproj fills attn's idle pipes.
// Attn path = R6 proven body (expf, lp on VALU, no ones-MFMA (R7), no setprio (R3)).
__global__ __launch_bounds__(256, 2) void k_attn_hiproj(
        const unsigned short* __restrict__ qbuf,  // [32768,256] m'-order
        const unsigned short* __restrict__ kbuf,  // [8192,256]
        const unsigned short* __restrict__ vT,    // [32][64][1024]
        unsigned short* __restrict__ aout,        // [32768,256] m'-order
        const unsigned short* __restrict__ dbuf,  // [32768,256] m'-order
        const unsigned short* __restrict__ hprojT,
        const float* __restrict__ h_proj_b,
        float* __restrict__ out) {
    __shared__ __align__(16) unsigned short smem[4 * 64 * 72];  // 36,864 B union (mm needs 32K)
    const int bx = blockIdx.x;
    const int tid = threadIdx.x;
    const int wave = tid >> 6, lane = tid & 63;
    const int m16 = lane & 15, quad = lane >> 4;

    if (bx < 512) {
        // ---------------- attention (R6 body) ----------------
        unsigned short* Kb = smem;                 // [2][64*72]
        unsigned short* Vb = smem + 2 * 64 * 72;   // [2][64*72]
        const int qtile = bx & 15, bh = bx >> 4;
        const int b = bh >> 2, h = bh & 3;

        bf16x8 qf[4][2];
        const size_t qrow0 = (size_t)b * 4096 + qtile * 256 + wave * 64;
#pragma unroll
        for (int qh = 0; qh < 4; qh++) {
            const unsigned short* qp = qbuf + (qrow0 + qh * 16 + m16) * 256 + h * 64 + quad * 8;
            qf[qh][0] = as_bf16x8(*(const u32x4*)qp);
            qf[qh][1] = as_bf16x8(*(const u32x4*)(qp + 32));
        }

        f32x4 o[4][4] = {};
        float lp[4] = {0.f, 0.f, 0.f, 0.f};

        const int sr = tid >> 3;       // 0..31
        const int sc = tid & 7;        // 16B chunk
        const unsigned short* kg = kbuf + ((size_t)b * 1024) * 256 + h * 64 + sc * 8;
        const unsigned short* vg = vT + ((size_t)bh * 64) * 1024 + sc * 8;

        u32x4 s0 = *(const u32x4*)(kg + (size_t)sr * 256);
        u32x4 s1 = *(const u32x4*)(kg + (size_t)(sr + 32) * 256);
        u32x4 s2 = *(const u32x4*)(vg + (size_t)sr * 1024);
        u32x4 s3 = *(const u32x4*)(vg + (size_t)(sr + 32) * 1024);
        *(u32x4*)&Kb[sr * 72 + sc * 8] = s0;
        *(u32x4*)&Kb[(sr + 32) * 72 + sc * 8] = s1;
        *(u32x4*)&Vb[sr * 72 + sc * 8] = s2;
        *(u32x4*)&Vb[(sr + 32) * 72 + sc * 8] = s3;

        for (int it = 0; it < 16; ++it) {
            const int cur = (it & 1) * 4608, nxt = cur ^ 4608;
            __syncthreads();
            if (it + 1 < 16) {
                const size_t kvb = (size_t)(it + 1) * 64;
                s0 = *(const u32x4*)(kg + (kvb + sr) * 256);
                s1 = *(const u32x4*)(kg + (kvb + sr + 32) * 256);
                s2 = *(const u32x4*)(vg + kvb + (size_t)sr * 1024);
                s3 = *(const u32x4*)(vg + kvb + (size_t)(sr + 32) * 1024);
            }

#pragma unroll
            for (int mt = 0; mt < 4; mt++) {
                // S^T = K Q^T : C col = q = m16, row = kv = mt*16 + quad*4 + r
                const unsigned short* kp = &Kb[cur + (mt * 16 + m16) * 72 + quad * 8];
                const bf16x8 kf0 = as_bf16x8(*(const u32x4*)kp);
                const bf16x8 kf1 = as_bf16x8(*(const u32x4*)(kp + 32));
                f32x4 st[4];
#pragma unroll
                for (int qh = 0; qh < 4; qh++) {
                    f32x4 z = {};
                    z = __builtin_amdgcn_mfma_f32_16x16x32_bf16(kf0, qf[qh][0], z, 0, 0, 0);
                    st[qh] = __builtin_amdgcn_mfma_f32_16x16x32_bf16(kf1, qf[qh][1], z, 0, 0, 0);
                }
                // P = exp(S*scale); packed P is directly the K=16 MFMA A-frag
                i16x4 pa[4];
#pragma unroll
                for (int qh = 0; qh < 4; qh++) {
                    float p0 = __expf(st[qh][0] * 0.125f);
                    float p1 = __expf(st[qh][1] * 0.125f);
                    float p2 = __expf(st[qh][2] * 0.125f);
                    float p3 = __expf(st[qh][3] * 0.125f);
                    lp[qh] += (p0 + p1) + (p2 + p3);
                    u16x4 pk = { f2bf(p0), f2bf(p1), f2bf(p2), f2bf(p3) };
                    pa[qh] = __builtin_bit_cast(i16x4, pk);
                }
#pragma unroll
                for (int nt = 0; nt < 4; nt++) {
                    const i16x4 vb = *(const i16x4*)&Vb[cur + (nt * 16 + m16) * 72 + mt * 16 + quad * 4];
#pragma unroll
                    for (int qh = 0; qh < 4; qh++)
                        o[qh][nt] = __builtin_amdgcn_mfma_f32_16x16x16bf16_1k(pa[qh], vb, o[qh][nt], 0, 0, 0);
                }
            }

            if (it + 1 < 16) {
                *(u32x4*)&Kb[nxt + sr * 72 + sc * 8] = s0;
                *(u32x4*)&Kb[nxt + (sr + 32) * 72 + sc * 8] = s1;
                *(u32x4*)&Vb[nxt + sr * 72 + sc * 8] = s2;
                *(u32x4*)&Vb[nxt + (sr + 32) * 72 + sc * 8] = s3;
            }
        }

#pragma unroll
        for (int qh = 0; qh < 4; qh++) {
            float l = lp[qh];
            l += __shfl_xor(l, 16);
            l += __shfl_xor(l, 32);
            f32x4 linv;
#pragma unroll
            for (int r = 0; r < 4; r++)
                linv[r] = __builtin_amdgcn_rcpf(__shfl(l, quad * 4 + r));
#pragma unroll
            for (int nt = 0; nt < 4; nt++)
#pragma unroll
                for (int r = 0; r < 4; r++)
                    aout[(qrow0 + qh * 16 + quad * 4 + r) * 256 + h * 64 + nt * 16 + m16] =
                        f2bf(o[qh][nt][r] * linv[r]);
        }
    } else {
        // ---------------- hi-fi projection GEMM ----------------
        unsigned short* As = smem;
        unsigned short* Bs = smem + 128 * 64;      // BK=64 core: 8192-short planes x2
        const int f = bx - 512;                    // 0..511
        const size_t row0 = (size_t)(f >> 1) * 128;
        const int col0 = (f & 1) * 128;

        f32x4 acc[4][4] = {};
        mm_core(dbuf, hprojT, row0, col0, 256, As, Bs, acc);

        const int wr = wave >> 1, wc = wave & 1;
#pragma unroll
        for (int mi = 0; mi < 4; mi++)
#pragma unroll
            for (int ni = 0; ni < 4; ni++) {
                const int col = col0 + wc * 64 + ni * 16 + m16;
                const float bv = h_proj_b[col];
                const size_t mb = row0 + wr * 64 + mi * 16 + quad * 4;
                const int widx = (int)(mb >> 2);
                const int b = widx >> 10, rem = widx & 1023;
                const int h2 = rem >> 5, w2 = rem & 31;
                const size_t nb = ((size_t)b << 12) + (h2 << 7) + (w2 << 1);
                float* op = out + nb * 512 + col;
                op[0]            = acc[mi][ni][0] + bv;
                op[512]          = acc[mi][ni][1] + bv;
                op[64 * 512]     = acc[mi][ni][2] + bv;
                op[65 * 512]     = acc[mi][ni][3] + bv;
            }
    }
}

// ---------------- launch 4: lo-fi projection GEMM, un-permuting epilogue ----------------
__global__ __launch_bounds__(256, 2) void k_mmproj_lo(
        const unsigned short* __restrict__ aout,
        const unsigned short* __restrict__ lprojT,
        const float* __restrict__ l_proj_b,
        float* __restrict__ out) {
    __shared__ __align__(16) unsigned short As[128 * 64];
    __shared__ __align__(16) unsigned short Bs[128 * 64];
    const int bid = blockIdx.x;                  // 0..511, 512%8==0 -> bijective
    const int f = (bid & 7) * 64 + (bid >> 3);
    const size_t row0 = (size_t)(f >> 1) * 128;
    const int col0 = (f & 1) * 128;

    f32x4 acc[4][4] = {};
    mm_core(aout, lprojT, row0, col0, 256, As, Bs, acc);

    const int tid = threadIdx.x;
    const int wave = tid >> 6, lane = tid & 63;
    const int m16 = lane & 15, quad = lane >> 4;
    const int wr = wave >> 1, wc = wave & 1;

#pragma unroll
    for (int mi = 0; mi < 4; mi++)
#pragma unroll
        for (int ni = 0; ni < 4; ni++) {
            const int col = col0 + wc * 64 + ni * 16 + m16;
            const float bv = l_proj_b[col];
            const size_t mb = row0 + wr * 64 + mi * 16 + quad * 4;
            const int widx = (int)(mb >> 2);
            const int b = widx >> 10, rem = widx & 1023;
            const int h2 = rem >> 5, w2 = rem & 31;
            const size_t nb = ((size_t)b << 12) + (h2 << 7) + (w2 << 1);
            float* op = out + nb * 512 + 256 + col;
            op[0]            = acc[mi][ni][0] + bv;
            op[512]          = acc[mi][ni][1] + bv;
            op[64 * 512]     = acc[mi][ni][2] + bv;
            op[65 * 512]     = acc[mi][ni][3] + bv;
        }
}

// ---------------- launcher ----------------

extern "C" void kernel_launch(void* const* d_in, const int* in_sizes, int n_in,
                              void* d_out, int out_size, void* d_ws, size_t ws_size,
                              hipStream_t stream) {
    (void)in_sizes; (void)n_in; (void)out_size; (void)ws_size;
    const float* x        = (const float*)d_in[0];
    const float* l_q_w    = (const float*)d_in[2];
    const float* l_kv_w   = (const float*)d_in[3];
    const float* l_proj_w = (const float*)d_in[4];
    const float* l_proj_b = (const float*)d_in[5];
    const float* h_qkv_w  = (const float*)d_in[6];
    const float* h_proj_w = (const float*)d_in[7];
    const float* h_proj_b = (const float*)d_in[8];
    float* out = (float*)d_out;

    char* ws = (char*)d_ws;
    unsigned short* xb     = (unsigned short*)(ws);             // 33.5MB, dead after mm512
    unsigned short* aout   = (unsigned short*)(ws);             // 16.8MB, overlays xb
    unsigned short* dbuf   = (unsigned short*)(ws + 33554432);  // 16.8MB
    unsigned short* qbuf   = (unsigned short*)(ws + 50331648);  // 16.8MB
    unsigned short* kbuf   = (unsigned short*)(ws + 67108864);  // 4.2MB
    unsigned short* vT     = (unsigned short*)(ws + 71303168);  // 4.2MB
    unsigned short* xpb    = (unsigned short*)(ws + 75497472);  // 8.4MB
    unsigned short* wcatT  = (unsigned short*)(ws + 83886080);
    unsigned short* lkvT   = (unsigned short*)(ws + 84410368);
    unsigned short* hprojT = (unsigned short*)(ws + 84934656);
    unsigned short* lprojT = (unsigned short*)(ws + 85065728);
    // total ws requirement: 85,196,800 B (same as prior rounds)

    // fused cast+pool (2048) + weight transpose (2560)
    k_prep<<<4608, 256, 0, stream>>>(x, h_qkv_w, l_q_w, l_kv_w, h_proj_w, l_proj_w,
                                     xb, xpb, wcatT, lkvT, hprojT, lprojT);
    // gemm1 (1024 blocks) + kv-gemm (256 blocks), fused hifi / V^T epilogues, XCD swizzle
    k_mm512<<<1280, 256, 0, stream>>>(xb, xpb, wcatT, lkvT, dbuf, qbuf, kbuf, vT);
    // attention (0..511) co-resident with hi-proj (512..1023)
    // (aout overlays xb -- xb dead after mm512)
    k_attn_hiproj<<<1024, 256, 0, stream>>>(qbuf, kbuf, vT, aout, dbuf, hprojT, h_proj_b, out);
    // lo-proj + bias + un-permute into out
    k_mmproj_lo<<<512, 256, 0, stream>>>(aout, lprojT, l_proj_b, out);
}